// Round 6
// baseline (352.875 us; speedup 1.0000x reference)
//
#include <hip/hip_runtime.h>
#include <stdint.h>

#define NUM_CLASSES 21
// ws layout: [0..20]=t_cnt, [21..41]=p_cnt, [42..62]=inter
#define WS_INTS (3 * NUM_CLASSES)

#define TILE_PIX 256
#define TILE_FLOATS (TILE_PIX * NUM_CLASSES)   // 5376 floats = 21504 B per tensor tile
#define CHUNKS 21                              // 1 KiB (64 lanes x 16 B) chunks per tile

__global__ void zero_ws_kernel(unsigned int* ws) {
    int i = threadIdx.x;
    if (i < WS_INTS) ws[i] = 0u;
}

// Async global->LDS DMA of one 1 KiB chunk: 64 lanes x 16 B contiguous.
// No VGPRs hold the data — this is what gets the live set under 32 regs.
__device__ __forceinline__ void async_copy_1k(const float* __restrict__ g, float* l, int lane) {
    __builtin_amdgcn_global_load_lds(
        (const __attribute__((address_space(1))) void*)(g + lane * 4),
        (__attribute__((address_space(3))) void*)l,
        16, 0, 0);
}

// Rationale (rounds 4+5): resident waves/CU are set by VGPR footprint, not grid.
// 52-VGPR build -> ~11 waves/CU -> 1.5 TB/s HBM; 32-VGPR build -> ~22 waves/CU
// -> 3.0 TB/s (round 4, but it spilled). This structure keeps data out of VGPRs
// entirely (DMA -> LDS, rolling argmax), single shared buffer (T then P phase)
// so LDS = 21.8 KB -> 7 blocks/CU. __launch_bounds__(256,8) budget = 64 VGPR;
// live set is ~20 regs, no spill possible.
__global__ __launch_bounds__(256, 8) void hist_kernel(const float* __restrict__ yt,
                                                      const float* __restrict__ yp,
                                                      unsigned int* __restrict__ ws,
                                                      long long npix) {
    __shared__ float buf[TILE_FLOATS];
    __shared__ unsigned int h[WS_INTS];

    const int tid  = threadIdx.x;
    const int wid  = tid >> 6;
    const int lane = tid & 63;

    for (int i = tid; i < WS_INTS; i += 256) h[i] = 0u;
    __syncthreads();

    const long long ntiles = npix >> 8;   // 8192 full 256-pixel tiles for this shape

    for (long long tile = blockIdx.x; tile < ntiles; tile += gridDim.x) {
        // ---- T phase: DMA tile into LDS (21 x 1 KiB chunks across 4 waves)
        {
            const float* tb = yt + tile * (long long)TILE_FLOATS;
            for (int c = wid; c < CHUNKS; c += 4)
                async_copy_1k(tb + c * 256, buf + c * 256, lane);
        }
        __syncthreads();   // drains vmcnt(0) -> tile visible

        // rolling argmax, 1 pixel/thread; LDS stride 21 floats (odd) -> 2 lanes/bank, free
        int ti;
        {
            const float* tp = buf + tid * NUM_CLASSES;
            float b = tp[0]; ti = 0;
#pragma unroll
            for (int c = 1; c < NUM_CLASSES; ++c) {
                float v = tp[c];
                if (v > b) { b = v; ti = c; }   // strict > == jnp.argmax first-max ties
            }
        }
        __syncthreads();   // all T reads done before P overwrites buf

        // ---- P phase: reuse the same buffer
        {
            const float* pb = yp + tile * (long long)TILE_FLOATS;
            for (int c = wid; c < CHUNKS; c += 4)
                async_copy_1k(pb + c * 256, buf + c * 256, lane);
        }
        __syncthreads();

        int pi;
        {
            const float* pp = buf + tid * NUM_CLASSES;
            float b = pp[0]; pi = 0;
#pragma unroll
            for (int c = 1; c < NUM_CLASSES; ++c) {
                float v = pp[c];
                if (v > b) { b = v; pi = c; }
            }
        }

        atomicAdd(&h[ti], 1u);
        atomicAdd(&h[NUM_CLASSES + pi], 1u);
        if (ti == pi) atomicAdd(&h[2 * NUM_CLASSES + ti], 1u);

        __syncthreads();   // all P reads done before next iteration's T stage
    }

    // ---- tail pixels (npix % 256 != 0) — not taken for 8*512*512
    if (blockIdx.x == 0) {
        for (long long pix = ntiles * TILE_PIX + tid; pix < npix; pix += 256) {
            const float* t = yt + pix * NUM_CLASSES;
            const float* p = yp + pix * NUM_CLASSES;
            float tb = t[0], pb = p[0];
            int tii = 0, pii = 0;
            for (int c = 1; c < NUM_CLASSES; ++c) {
                if (t[c] > tb) { tb = t[c]; tii = c; }
                if (p[c] > pb) { pb = p[c]; pii = c; }
            }
            atomicAdd(&h[tii], 1u);
            atomicAdd(&h[NUM_CLASSES + pii], 1u);
            if (tii == pii) atomicAdd(&h[2 * NUM_CLASSES + tii], 1u);
        }
    }

    __syncthreads();
    for (int i = tid; i < WS_INTS; i += 256) {
        if (h[i]) atomicAdd(&ws[i], h[i]);
    }
}

__global__ void finalize_kernel(const unsigned int* __restrict__ ws,
                                float* __restrict__ out) {
    int c = threadIdx.x;  // one wave
    float iou = 0.0f, valid = 0.0f;
    if (c < NUM_CLASSES) {
        float inter = (float)ws[2 * NUM_CLASSES + c];
        float uni   = (float)ws[c] + (float)ws[NUM_CLASSES + c] - inter;
        if (uni > 0.0f) { iou = inter / uni; valid = 1.0f; }
    }
#pragma unroll
    for (int off = 32; off > 0; off >>= 1) {
        iou   += __shfl_down(iou, off);
        valid += __shfl_down(valid, off);
    }
    if (c == 0) out[0] = iou / valid;
}

extern "C" void kernel_launch(void* const* d_in, const int* in_sizes, int n_in,
                              void* d_out, int out_size, void* d_ws, size_t ws_size,
                              hipStream_t stream) {
    const float* y_true = (const float*)d_in[0];
    const float* y_pred = (const float*)d_in[1];
    float* out = (float*)d_out;
    unsigned int* ws = (unsigned int*)d_ws;

    long long total = (long long)in_sizes[0];   // 44,040,192
    long long npix  = total / NUM_CLASSES;      // 2,097,152

    int block = 256;
    int grid  = 2048;   // 7 blocks/CU resident (LDS 21.8 KB); 4 tiles per block

    zero_ws_kernel<<<1, 64, 0, stream>>>(ws);
    hist_kernel<<<grid, block, 0, stream>>>(y_true, y_pred, ws, npix);
    finalize_kernel<<<1, 64, 0, stream>>>(ws, out);
}